// Round 19
// baseline (282.375 us; speedup 1.0000x reference)
//
#include <hip/hip_runtime.h>
#include <stdint.h>

#define D_MODEL 2048
#define N_HEADS 16
#define HEAD_D  128
#define BATCH   2
#define SEQ     2048
#define MTOT    (BATCH*SEQ)   // 4096

typedef __bf16 bf16x8 __attribute__((ext_vector_type(8)));
typedef float  f32x4  __attribute__((ext_vector_type(4)));
typedef unsigned short u16x8 __attribute__((ext_vector_type(8)));
typedef unsigned short u16x4 __attribute__((ext_vector_type(4)));

#define MFMA16(a,b,c) __builtin_amdgcn_mfma_f32_16x16x32_bf16(a, b, c, 0, 0, 0)

__device__ __forceinline__ unsigned short f2bf(float f) {
  unsigned u = __builtin_bit_cast(unsigned, f);
  u += 0x7fffu + ((u >> 16) & 1u);
  return (unsigned short)(u >> 16);
}

__device__ __forceinline__ bf16x8 ld_frag(const unsigned short* p) {
  u16x8 raw = *(const u16x8*)p;
  return __builtin_bit_cast(bf16x8, raw);
}

__device__ __forceinline__ void gload16(const void* g, void* lds) {
  __builtin_amdgcn_global_load_lds(
      (const __attribute__((address_space(1))) unsigned int*)g,
      (__attribute__((address_space(3))) unsigned int*)lds, 16, 0, 0);
}

// ---------------- fp32 -> bf16 conversion, single dispatch (x + all 4 weights) ------
__global__ __launch_bounds__(256) void f32_to_bf16_all(const float* __restrict__ x,
                                                       const float* __restrict__ w0,
                                                       const float* __restrict__ w1,
                                                       const float* __restrict__ w2,
                                                       const float* __restrict__ w3,
                                                       unsigned short* __restrict__ out) {
  const int i = blockIdx.x * 256 + threadIdx.x;   // < 3*2^20
  const float* s;
  int r;
  if (i < (1 << 20)) {              // x: 4096*2048/8 = 2^20 chunks
    s = x; r = i;
  } else {
    const int j = i - (1 << 20);    // weights: 4 * 2^19 chunks
    const int which = j >> 19;
    r = j & ((1 << 19) - 1);
    s = (which == 0) ? w0 : (which == 1) ? w1 : (which == 2) ? w2 : w3;
  }
  const float4* p = (const float4*)s + (size_t)r * 2;
  float4 a = p[0], b = p[1];
  u16x8 o;
  o[0] = f2bf(a.x); o[1] = f2bf(a.y); o[2] = f2bf(a.z); o[3] = f2bf(a.w);
  o[4] = f2bf(b.x); o[5] = f2bf(b.y); o[6] = f2bf(b.z); o[7] = f2bf(b.w);
  *((u16x8*)out + i) = o;
}

// ---------------- m97-style 128x128 GEMM (O-projection) ----------------
__global__ __launch_bounds__(256) void gemm_bt_f32(const unsigned short* __restrict__ A,
                                                   const unsigned short* __restrict__ B,
                                                   float* __restrict__ C,
                                                   int M, int N, int K) {
  __shared__ __align__(16) unsigned short As[128 * 32];
  __shared__ __align__(16) unsigned short Bs[128 * 32];
  const int tid  = threadIdx.x;
  const int lane = tid & 63;
  const int w    = tid >> 6;
  const int wr   = w >> 1, wc = w & 1;

  const int gx = gridDim.x;
  int bx = blockIdx.x, by = blockIdx.y;
  const int nwg = gx * gridDim.y;
  if ((nwg & 7) == 0) {
    const int lid = by * gx + bx;
    const int cpx = nwg >> 3;
    const int swz = (lid & 7) * cpx + (lid >> 3);
    bx = swz % gx; by = swz / gx;
  }
  const int brow = by * 128;
  const int bcol = bx * 128;

  const int e0 = (w * 2) * 512 + lane * 8;
  const int e1 = (w * 2 + 1) * 512 + lane * 8;
  const int r0 = e0 >> 5, cc0 = e0 & 31;
  const int r1 = e1 >> 5, cc1 = e1 & 31;
  const unsigned short* Ap0 = A + (size_t)(brow + r0) * K + cc0;
  const unsigned short* Ap1 = A + (size_t)(brow + r1) * K + cc1;
  const unsigned short* Bp0 = B + (size_t)(bcol + r0) * K + cc0;
  const unsigned short* Bp1 = B + (size_t)(bcol + r1) * K + cc1;
  unsigned short* As0 = &As[(w * 2) * 512];
  unsigned short* As1 = &As[(w * 2 + 1) * 512];
  unsigned short* Bs0 = &Bs[(w * 2) * 512];
  unsigned short* Bs1 = &Bs[(w * 2 + 1) * 512];

  f32x4 acc[4][4] = {};
  const int la = lane & 15;
  const int lb = (lane >> 4) * 8;

  for (int kt = 0; kt < K; kt += 32) {
    gload16(Ap0 + kt, As0);
    gload16(Ap1 + kt, As1);
    gload16(Bp0 + kt, Bs0);
    gload16(Bp1 + kt, Bs1);
    __syncthreads();
    bf16x8 af[4], bfr[4];
#pragma unroll
    for (int m = 0; m < 4; ++m)
      af[m] = ld_frag(&As[(wr * 64 + m * 16 + la) * 32 + lb]);
#pragma unroll
    for (int n = 0; n < 4; ++n)
      bfr[n] = ld_frag(&Bs[(wc * 64 + n * 16 + la) * 32 + lb]);
#pragma unroll
    for (int m = 0; m < 4; ++m)
#pragma unroll
      for (int n = 0; n < 4; ++n)
        acc[m][n] = MFMA16(af[m], bfr[n], acc[m][n]);
    __syncthreads();
  }

  const int rowb = (lane >> 4) * 4;
#pragma unroll
  for (int m = 0; m < 4; ++m)
#pragma unroll
    for (int n = 0; n < 4; ++n) {
      const int gcol = bcol + wc * 64 + n * 16 + la;
      const int grow0 = brow + wr * 64 + m * 16 + rowb;
#pragma unroll
      for (int j = 0; j < 4; ++j)
        C[(size_t)(grow0 + j) * N + gcol] = acc[m][n][j];
    }
}

// ---------------- 256x256 fused QKV GEMM, v4b (no setprio; r18: 125.8 us) ----------------
#define SQ_STAGE_HALF(T2, HF)                                                     \
  do {                                                                            \
    const int kt2_ = (T2) * 64;                                                   \
    _Pragma("unroll")                                                             \
    for (int s_ = 0; s_ < 2; ++s_) {                                              \
      const int idx_ = s_ * 512 + tid;                                            \
      const int sub_ = idx_ >> 6;                                                 \
      const int rin_ = (idx_ >> 2) & 15;                                          \
      const int cby_ = (idx_ & 3) * 16;                                           \
      const int r_   = ((HF) & 1) * 128 + (sub_ >> 1) * 16 + rin_;                \
      const int ce_  = (sub_ & 1) * 32 + ((cby_ ^ ((rin_ & 8) << 2)) >> 1);       \
      const unsigned short* gp_ = ((HF) < 2)                                      \
          ? (Ag + (size_t)(brow + r_) * 2048 + kt2_ + ce_)                        \
          : (Bg + (size_t)(bcol + r_) * 2048 + kt2_ + ce_);                       \
      gload16(gp_, SB + ((((T2) & 1) * 65536 + ((HF) >> 1) * 32768 +              \
                          ((HF) & 1) * 16384 + (s_ * 512 + w * 64) * 16) >> 1));  \
    }                                                                             \
  } while (0)

#define SQ_STAGE_ALL(T2)                                                          \
  do { SQ_STAGE_HALF(T2, 0); SQ_STAGE_HALF(T2, 1);                                \
       SQ_STAGE_HALF(T2, 2); SQ_STAGE_HALF(T2, 3); } while (0)

#define SQ_MFMA16x(AF, BF, MOFF)                                                  \
  do {                                                                            \
    _Pragma("unroll") for (int m_ = 0; m_ < 4; ++m_)                              \
      _Pragma("unroll") for (int n_ = 0; n_ < 4; ++n_)                            \
        acc[(MOFF) + m_][n_] = MFMA16(AF[m_], BF[n_], acc[(MOFF) + m_][n_]);      \
  } while (0)

#define SQ_TILE(CUR)                                                              \
  do {                                                                            \
    const char* Ab_ = (const char*)SB + (CUR) * 65536 + wr * 16384;               \
    const char* Bb_ = (const char*)SB + (CUR) * 65536 + 32768 +                   \
                      (wcn >> 1) * 16384 + (wcn & 1) * 8192;                      \
    bf16x8 a0_[4], a1_[4], a2_[4], a3_[4], b0_[4], b1_[4];                        \
    _Pragma("unroll") for (int n_ = 0; n_ < 4; ++n_)                              \
      b0_[n_] = ld_frag((const unsigned short*)(Bb_ + n_ * 2048 + la * 64 + cxa));\
    _Pragma("unroll") for (int m_ = 0; m_ < 4; ++m_)                              \
      a0_[m_] = ld_frag((const unsigned short*)(Ab_ + m_ * 2048 + la * 64 + cxa));\
    _Pragma("unroll") for (int m_ = 0; m_ < 4; ++m_)                              \
      a1_[m_] = ld_frag((const unsigned short*)(Ab_ + (4 + m_) * 2048 + la * 64 + cxa)); \
    asm volatile("s_waitcnt lgkmcnt(4)" ::: "memory");                            \
    __builtin_amdgcn_sched_barrier(0);                                            \
    SQ_MFMA16x(a0_, b0_, 0);                                                      \
    _Pragma("unroll") for (int n_ = 0; n_ < 4; ++n_)                              \
      b1_[n_] = ld_frag((const unsigned short*)(Bb_ + n_ * 2048 + 1024 + la * 64 + cxa)); \
    _Pragma("unroll") for (int m_ = 0; m_ < 4; ++m_)                              \
      a2_[m_] = ld_frag((const unsigned short*)(Ab_ + m_ * 2048 + 1024 + la * 64 + cxa)); \
    asm volatile("s_waitcnt lgkmcnt(8)" ::: "memory");                            \
    __builtin_amdgcn_sched_barrier(0);                                            \
    SQ_MFMA16x(a1_, b0_, 4);                                                      \
    _Pragma("unroll") for (int m_ = 0; m_ < 4; ++m_)                              \
      a3_[m_] = ld_frag((const unsigned short*)(Ab_ + (4 + m_) * 2048 + 1024 + la * 64 + cxa)); \
    asm volatile("s_waitcnt lgkmcnt(4)" ::: "memory");                            \
    __builtin_amdgcn_sched_barrier(0);                                            \
    SQ_MFMA16x(a2_, b1_, 0);                                                      \
    asm volatile("s_waitcnt lgkmcnt(0)" ::: "memory");                            \
    __builtin_amdgcn_sched_barrier(0);                                            \
    SQ_MFMA16x(a3_, b1_, 4);                                                      \
  } while (0)

__global__ __launch_bounds__(512, 1)
__attribute__((amdgpu_waves_per_eu(1, 2)))
void gemm_qkv256(const unsigned short* __restrict__ Ag,
                 const unsigned short* __restrict__ Bg,
                 unsigned short* __restrict__ Qp,
                 unsigned short* __restrict__ Kp,
                 unsigned short* __restrict__ Vtp) {
  __shared__ __align__(16) unsigned short SB[65536];   // 128 KiB
  const int tid = threadIdx.x, lane = tid & 63, w = tid >> 6;
  const int wr = w >> 2, wcn = w & 3;
  const int la = lane & 15, hi = lane >> 4;
  const int cxa = (hi * 16) ^ ((lane & 8) << 2);

  const int gx = gridDim.x;
  const int nwg = gx * gridDim.y;
  const int lid = blockIdx.y * gx + blockIdx.x;
  const int cpx = nwg >> 3;
  const int sz = (lid & 7) * cpx + (lid >> 3);
  const int bx = sz % gx, by = sz / gx;
  const int brow = by * 256, bcol = bx * 256;

  f32x4 acc[8][4] = {};

  SQ_STAGE_ALL(0);

#pragma unroll 1
  for (int t = 0; t < 32; ++t) {
    const int cur = t & 1;
    if (t < 31) {
      SQ_STAGE_ALL(t + 1);
      asm volatile("s_waitcnt vmcnt(8)" ::: "memory");
    } else {
      asm volatile("s_waitcnt vmcnt(0)" ::: "memory");
    }
    __builtin_amdgcn_sched_barrier(0);
    __builtin_amdgcn_s_barrier();

    SQ_TILE(cur);

    __builtin_amdgcn_s_barrier();
  }

  // epilogue: scatter Q (which=0), K (which=1), V^T (which=2)
#pragma unroll
  for (int mg = 0; mg < 8; ++mg) {
#pragma unroll
    for (int ng = 0; ng < 4; ++ng) {
      const int gcol = bcol + wcn * 64 + ng * 16 + la;
      const int grow0 = brow + wr * 128 + mg * 16 + hi * 4;
      const int which = gcol >> 11;
      const int c2 = gcol & 2047;
      const int hh = c2 >> 7, dd = c2 & 127;
      const int bb = grow0 >> 11, tt = grow0 & (SEQ - 1);
      if (which == 2) {
        u16x4 pk;
#pragma unroll
        for (int j = 0; j < 4; ++j) pk[j] = f2bf(acc[mg][ng][j]);
        *(u16x4*)&Vtp[(((size_t)bb * N_HEADS + hh) * HEAD_D + dd) * SEQ + tt] = pk;
      } else {
        unsigned short* dst = which ? Kp : Qp;
#pragma unroll
        for (int j = 0; j < 4; ++j)
          dst[(((size_t)bb * N_HEADS + hh) * SEQ + tt + j) * HEAD_D + dd] = f2bf(acc[mg][ng][j]);
      }
    }
  }
}

// ---------------- causal ALiBi flash attention (r17 minus setprio) ----------------
#define STAGE_KV(U, BSEL)                                                           \
  do {                                                                              \
    const int kv0_ = (((U) <= qtA) ? (U) : (U) - qtA - 1) * 64;                     \
    _Pragma("unroll")                                                               \
    for (int s = 0; s < 4; ++s) {                                                   \
      const int p_ = (w * 4 + s) * 1024 + lane * 16;                                \
      const int row_ = p_ >> 8, cb_ = p_ & 255;                                     \
      const int col_ = (cb_ ^ ((row_ & 7) << 4)) >> 1;                              \
      gload16(&K[kbase + (size_t)(kv0_ + row_) * HEAD_D + col_],                    \
              &Ks[BSEL][(w * 4 + s) * 512]);                                        \
    }                                                                               \
    _Pragma("unroll")                                                               \
    for (int s = 0; s < 4; ++s) {                                                   \
      const int p_ = (w * 4 + s) * 1024 + lane * 16;                                \
      const int d_ = p_ >> 7, cb_ = p_ & 127;                                       \
      const int col_ = (cb_ ^ ((d_ & 7) << 4)) >> 1;                                \
      gload16(&VT[vtbase + (size_t)d_ * SEQ + kv0_ + col_],                         \
              &Vs[BSEL][(w * 4 + s) * 512]);                                        \
    }                                                                               \
  } while (0)

#define LOAD_Q(Q0)                                                                  \
  do {                                                                              \
    const size_t qa_ = ((size_t)bh * SEQ + (Q0) + w * 16 + la) * HEAD_D + lq * 8;   \
    _Pragma("unroll")                                                               \
    for (int kk = 0; kk < 4; ++kk) qf[kk] = ld_frag(&Q[qa_ + kk * 32]);             \
  } while (0)

#define EPILOGUE(Q0)                                                                \
  do {                                                                              \
    _Pragma("unroll")                                                               \
    for (int j = 0; j < 4; ++j) {                                                   \
      const float inv_ = 1.0f / lrow[j];                                            \
      const int q_ = (Q0) + w * 16 + lq * 4 + j;                                    \
      const size_t ob_ = ((size_t)b * SEQ + q_) * D_MODEL + (size_t)h * HEAD_D;     \
      _Pragma("unroll")                                                             \
      for (int n = 0; n < 8; ++n) O[ob_ + n * 16 + la] = f2bf(acc[n][j] * inv_);    \
    }                                                                               \
  } while (0)

// step-major cross-lane reduces: the 4 rows' shfl chains interleave (~1/4 latency)
#define SOFTMAX_TILE(S, QG0, DIAG, KV0)                                            \
  do {                                                                             \
    float corr_[4];                                                                \
    float pe_[4][4];                                                               \
    float mx_[4];                                                                  \
    float rs_[4];                                                                  \
    _Pragma("unroll")                                                              \
    for (int j = 0; j < 4; ++j) {                                                  \
      const int qgj_ = (QG0) + j;                                                  \
      float m_ = -1e30f;                                                           \
      _Pragma("unroll")                                                            \
      for (int c = 0; c < 4; ++c) {                                                \
        const int kvg_ = (KV0) + c * 16 + la;                                      \
        float sv_ = fmaf(S[c][j], scale, slope * (float)(kvg_ - qgj_));            \
        if ((DIAG) && (kvg_ > qgj_)) sv_ = -1e30f;                                 \
        pe_[c][j] = sv_;                                                           \
        m_ = fmaxf(m_, sv_);                                                       \
      }                                                                            \
      mx_[j] = m_;                                                                 \
    }                                                                              \
    _Pragma("unroll")                                                              \
    for (int st = 1; st <= 8; st <<= 1) {                                          \
      _Pragma("unroll")                                                            \
      for (int j = 0; j < 4; ++j) mx_[j] = fmaxf(mx_[j], __shfl_xor(mx_[j], st));  \
    }                                                                              \
    _Pragma("unroll")                                                              \
    for (int j = 0; j < 4; ++j) {                                                  \
      const float nm_ = fmaxf(mrow[j], mx_[j]);                                    \
      corr_[j] = __expf(mrow[j] - nm_);                                            \
      mrow[j] = nm_;                                                               \
      float r_ = 0.f;                                                              \
      _Pragma("unroll")                                                            \
      for (int c = 0; c < 4; ++c) {                                                \
        const float e_ = __expf(pe_[c][j] - nm_);                                  \
        pe_[c][j] = e_;                                                            \
        r_ += e_;                                                                  \
      }                                                                            \
      rs_[j] = r_;                                                                 \
    }                                                                              \
    _Pragma("unroll")                                                              \
    for (int st = 1; st <= 8; st <<= 1) {                                          \
      _Pragma("unroll")                                                            \
      for (int j = 0; j < 4; ++j) rs_[j] += __shfl_xor(rs_[j], st);                \
    }                                                                              \
    _Pragma("unroll")                                                              \
    for (int j = 0; j < 4; ++j) lrow[j] = lrow[j] * corr_[j] + rs_[j];             \
    _Pragma("unroll")                                                              \
    for (int n = 0; n < 8; ++n) {                                                  \
      _Pragma("unroll")                                                            \
      for (int j = 0; j < 4; ++j) acc[n][j] *= corr_[j];                           \
    }                                                                              \
    _Pragma("unroll")                                                              \
    for (int c = 0; c < 4; ++c) {                                                  \
      _Pragma("unroll")                                                            \
      for (int j = 0; j < 4; ++j) {                                                \
        const int row_ = lq * 4 + j;                                               \
        const int cb_ = (c * 16 + la) * 2;                                         \
        *(unsigned short*)((char*)Ps[w] + row_ * 128 + (cb_ ^ ((row_ & 7) << 4)))  \
            = f2bf(pe_[c][j]);                                                     \
      }                                                                            \
    }                                                                              \
  } while (0)

__global__ __launch_bounds__(256)
void attn_k(const unsigned short* __restrict__ Q,
            const unsigned short* __restrict__ K,
            const unsigned short* __restrict__ VT,
            unsigned short* __restrict__ O) {
  __shared__ __align__(16) unsigned short Ks[2][64 * HEAD_D];   // 2x16 KB
  __shared__ __align__(16) unsigned short Vs[2][HEAD_D * 64];   // 2x16 KB
  __shared__ __align__(16) unsigned short Ps[4][16 * 64];       // 8 KB  (72 KB total)

  const int tid = threadIdx.x, lane = tid & 63, w = tid >> 6;
  const int lid = blockIdx.x;
  const int swz = (lid & 7) * 64 + (lid >> 3);
  const int qp = swz & 15;
  const int h  = (swz >> 4) & 15;
  const int b  = swz >> 8;
  const int bh = b * N_HEADS + h;
  const int qtA = qp, qtB = 31 - qp;
  const int q0A = qtA * 64, q0B = qtB * 64;

  const float slope = exp2f(-0.5f * (float)(h + 1));
  const float scale = 0.08838834764831845f;   // 1/sqrt(128)
  const int la = lane & 15;
  const int lq = lane >> 4;

  const size_t kbase  = (size_t)bh * SEQ * HEAD_D;
  const size_t vtbase = (size_t)bh * HEAD_D * SEQ;

  bf16x8 qf[4];
  f32x4 acc[8] = {};
  float mrow[4] = {-1e30f, -1e30f, -1e30f, -1e30f};
  float lrow[4] = {0.f, 0.f, 0.f, 0.f};
  int q0cur = q0A;

  LOAD_Q(q0A);
  STAGE_KV(0, 0);

  for (int u = 0; u < 33; ++u) {
    if (u < 32) {
      STAGE_KV(u + 1, (u + 1) & 1);
      asm volatile("s_waitcnt vmcnt(8)" ::: "memory");
    } else {
      asm volatile("s_waitcnt vmcnt(0)" ::: "memory");
    }
    __builtin_amdgcn_sched_barrier(0);
    __builtin_amdgcn_s_barrier();

    if (u == qtA + 1) {
      EPILOGUE(q0A);
      LOAD_Q(q0B);
      q0cur = q0B;
#pragma unroll
      for (int n = 0; n < 8; ++n)
#pragma unroll
        for (int j = 0; j < 4; ++j) acc[n][j] = 0.f;
#pragma unroll
      for (int j = 0; j < 4; ++j) { mrow[j] = -1e30f; lrow[j] = 0.f; }
    }

    const int cur = u & 1;
    const int kv0 = ((u <= qtA) ? u : u - qtA - 1) * 64;
    const bool diag = (u == qtA) || (u == 32);

    f32x4 s4[4] = {{0.f,0.f,0.f,0.f},{0.f,0.f,0.f,0.f},{0.f,0.f,0.f,0.f},{0.f,0.f,0.f,0.f}};
#pragma unroll
    for (int c = 0; c < 4; ++c) {
      const int row = c * 16 + la;
#pragma unroll
      for (int kk = 0; kk < 4; ++kk) {
        const int cb = kk * 64 + lq * 16;
        bf16x8 kf = ld_frag((const unsigned short*)((const char*)Ks[cur] + row * 256 + (cb ^ ((row & 7) << 4))));
        s4[c] = MFMA16(qf[kk], kf, s4[c]);
      }
    }

    SOFTMAX_TILE(s4, q0cur + w * 16 + lq * 4, diag, kv0);

    asm volatile("s_waitcnt lgkmcnt(0)" ::: "memory");
    __builtin_amdgcn_sched_barrier(0);

#pragma unroll
    for (int kk = 0; kk < 2; ++kk) {
      const int pcb = kk * 64 + lq * 16;
      const int paddr = la * 128 + (pcb ^ ((la & 7) << 4));
      bf16x8 pf = ld_frag((const unsigned short*)((const char*)Ps[w] + paddr));
#pragma unroll
      for (int n = 0; n < 8; ++n) {
        const int d = n * 16 + la;
        bf16x8 vf = ld_frag((const unsigned short*)((const char*)Vs[cur] + d * 128 + (pcb ^ ((d & 7) << 4))));
        acc[n] = MFMA16(pf, vf, acc[n]);
      }
    }

    __builtin_amdgcn_s_barrier();
  }

  EPILOGUE(q0B);
}

// ---------------- launcher ----------------
extern "C" void kernel_launch(void* const* d_in, const int* in_sizes, int n_in,
                              void* d_out, int out_size, void* d_ws, size_t ws_size,
                              hipStream_t stream) {
  (void)in_sizes; (void)n_in; (void)out_size; (void)ws_size;
  const float* x  = (const float*)d_in[0];
  const float* Wq = (const float*)d_in[1];
  const float* Wk = (const float*)d_in[2];
  const float* Wv = (const float*)d_in[3];
  const float* Wo = (const float*)d_in[4];

  char* ws = (char*)d_ws;
  unsigned short* xb = (unsigned short*)(ws + 0);          // 16 MiB
  unsigned short* wq = (unsigned short*)(ws + 16777216);   // 8 MiB  (wq|wk|wv|wo contiguous)
  unsigned short* wo = (unsigned short*)(ws + 41943040);   // 8 MiB
  unsigned short* q  = (unsigned short*)(ws + 50331648);   // 16 MiB
  unsigned short* k  = (unsigned short*)(ws + 67108864);   // 16 MiB
  unsigned short* vt = (unsigned short*)(ws + 83886080);   // 16 MiB
  unsigned short* o  = (unsigned short*)(ws + 0);          // aliases xb (dead after QKV GEMM)

  // one conversion dispatch: x (2^20 chunks) then wq|wk|wv|wo (2^21 chunks)
  f32_to_bf16_all<<<12288, 256, 0, stream>>>(x, Wq, Wk, Wv, Wo, xb);

  // fused QKV projection, v4b: grid (N/256, M/256) = (24, 16)
  gemm_qkv256<<<dim3(3 * D_MODEL / 256, MTOT / 256), 512, 0, stream>>>(xb, wq, q, k, vt);

  attn_k<<<512, 256, 0, stream>>>(q, k, vt, o);

  // O-projection (m97 structure, fp32 out)
  dim3 g2(D_MODEL / 128, MTOT / 128);       // (16, 32)
  gemm_bt_f32<<<g2, 256, 0, stream>>>(o, wo, (float*)d_out, MTOT, D_MODEL, D_MODEL);
}

// Round 20
// 281.163 us; speedup vs baseline: 1.0043x; 1.0043x over previous
//
#include <hip/hip_runtime.h>
#include <stdint.h>

#define D_MODEL 2048
#define N_HEADS 16
#define HEAD_D  128
#define BATCH   2
#define SEQ     2048
#define MTOT    (BATCH*SEQ)   // 4096

typedef __bf16 bf16x8 __attribute__((ext_vector_type(8)));
typedef float  f32x4  __attribute__((ext_vector_type(4)));
typedef unsigned short u16x8 __attribute__((ext_vector_type(8)));
typedef unsigned short u16x4 __attribute__((ext_vector_type(4)));

#define MFMA16(a,b,c) __builtin_amdgcn_mfma_f32_16x16x32_bf16(a, b, c, 0, 0, 0)

__device__ __forceinline__ unsigned short f2bf(float f) {
  unsigned u = __builtin_bit_cast(unsigned, f);
  u += 0x7fffu + ((u >> 16) & 1u);
  return (unsigned short)(u >> 16);
}

__device__ __forceinline__ bf16x8 ld_frag(const unsigned short* p) {
  u16x8 raw = *(const u16x8*)p;
  return __builtin_bit_cast(bf16x8, raw);
}

__device__ __forceinline__ void gload16(const void* g, void* lds) {
  __builtin_amdgcn_global_load_lds(
      (const __attribute__((address_space(1))) unsigned int*)g,
      (__attribute__((address_space(3))) unsigned int*)lds, 16, 0, 0);
}

// ---------------- fp32 -> bf16 conversion, single dispatch (x + all 4 weights) ------
__global__ __launch_bounds__(256) void f32_to_bf16_all(const float* __restrict__ x,
                                                       const float* __restrict__ w0,
                                                       const float* __restrict__ w1,
                                                       const float* __restrict__ w2,
                                                       const float* __restrict__ w3,
                                                       unsigned short* __restrict__ out) {
  const int i = blockIdx.x * 256 + threadIdx.x;   // < 3*2^20
  const float* s;
  int r;
  if (i < (1 << 20)) {              // x: 4096*2048/8 = 2^20 chunks
    s = x; r = i;
  } else {
    const int j = i - (1 << 20);    // weights: 4 * 2^19 chunks
    const int which = j >> 19;
    r = j & ((1 << 19) - 1);
    s = (which == 0) ? w0 : (which == 1) ? w1 : (which == 2) ? w2 : w3;
  }
  const float4* p = (const float4*)s + (size_t)r * 2;
  float4 a = p[0], b = p[1];
  u16x8 o;
  o[0] = f2bf(a.x); o[1] = f2bf(a.y); o[2] = f2bf(a.z); o[3] = f2bf(a.w);
  o[4] = f2bf(b.x); o[5] = f2bf(b.y); o[6] = f2bf(b.z); o[7] = f2bf(b.w);
  *((u16x8*)out + i) = o;
}

// ---------------- m97-style 128x128 GEMM (O-projection) ----------------
__global__ __launch_bounds__(256) void gemm_bt_f32(const unsigned short* __restrict__ A,
                                                   const unsigned short* __restrict__ B,
                                                   float* __restrict__ C,
                                                   int M, int N, int K) {
  __shared__ __align__(16) unsigned short As[128 * 32];
  __shared__ __align__(16) unsigned short Bs[128 * 32];
  const int tid  = threadIdx.x;
  const int lane = tid & 63;
  const int w    = tid >> 6;
  const int wr   = w >> 1, wc = w & 1;

  const int gx = gridDim.x;
  int bx = blockIdx.x, by = blockIdx.y;
  const int nwg = gx * gridDim.y;
  if ((nwg & 7) == 0) {
    const int lid = by * gx + bx;
    const int cpx = nwg >> 3;
    const int swz = (lid & 7) * cpx + (lid >> 3);
    bx = swz % gx; by = swz / gx;
  }
  const int brow = by * 128;
  const int bcol = bx * 128;

  const int e0 = (w * 2) * 512 + lane * 8;
  const int e1 = (w * 2 + 1) * 512 + lane * 8;
  const int r0 = e0 >> 5, cc0 = e0 & 31;
  const int r1 = e1 >> 5, cc1 = e1 & 31;
  const unsigned short* Ap0 = A + (size_t)(brow + r0) * K + cc0;
  const unsigned short* Ap1 = A + (size_t)(brow + r1) * K + cc1;
  const unsigned short* Bp0 = B + (size_t)(bcol + r0) * K + cc0;
  const unsigned short* Bp1 = B + (size_t)(bcol + r1) * K + cc1;
  unsigned short* As0 = &As[(w * 2) * 512];
  unsigned short* As1 = &As[(w * 2 + 1) * 512];
  unsigned short* Bs0 = &Bs[(w * 2) * 512];
  unsigned short* Bs1 = &Bs[(w * 2 + 1) * 512];

  f32x4 acc[4][4] = {};
  const int la = lane & 15;
  const int lb = (lane >> 4) * 8;

  for (int kt = 0; kt < K; kt += 32) {
    gload16(Ap0 + kt, As0);
    gload16(Ap1 + kt, As1);
    gload16(Bp0 + kt, Bs0);
    gload16(Bp1 + kt, Bs1);
    __syncthreads();
    bf16x8 af[4], bfr[4];
#pragma unroll
    for (int m = 0; m < 4; ++m)
      af[m] = ld_frag(&As[(wr * 64 + m * 16 + la) * 32 + lb]);
#pragma unroll
    for (int n = 0; n < 4; ++n)
      bfr[n] = ld_frag(&Bs[(wc * 64 + n * 16 + la) * 32 + lb]);
#pragma unroll
    for (int m = 0; m < 4; ++m)
#pragma unroll
      for (int n = 0; n < 4; ++n)
        acc[m][n] = MFMA16(af[m], bfr[n], acc[m][n]);
    __syncthreads();
  }

  const int rowb = (lane >> 4) * 4;
#pragma unroll
  for (int m = 0; m < 4; ++m)
#pragma unroll
    for (int n = 0; n < 4; ++n) {
      const int gcol = bcol + wc * 64 + n * 16 + la;
      const int grow0 = brow + wr * 64 + m * 16 + rowb;
#pragma unroll
      for (int j = 0; j < 4; ++j)
        C[(size_t)(grow0 + j) * N + gcol] = acc[m][n][j];
    }
}

// ---------------- 256x256 fused QKV GEMM, v4b (no setprio; r18: 125.8 us) ----------------
#define SQ_STAGE_HALF(T2, HF)                                                     \
  do {                                                                            \
    const int kt2_ = (T2) * 64;                                                   \
    _Pragma("unroll")                                                             \
    for (int s_ = 0; s_ < 2; ++s_) {                                              \
      const int idx_ = s_ * 512 + tid;                                            \
      const int sub_ = idx_ >> 6;                                                 \
      const int rin_ = (idx_ >> 2) & 15;                                          \
      const int cby_ = (idx_ & 3) * 16;                                           \
      const int r_   = ((HF) & 1) * 128 + (sub_ >> 1) * 16 + rin_;                \
      const int ce_  = (sub_ & 1) * 32 + ((cby_ ^ ((rin_ & 8) << 2)) >> 1);       \
      const unsigned short* gp_ = ((HF) < 2)                                      \
          ? (Ag + (size_t)(brow + r_) * 2048 + kt2_ + ce_)                        \
          : (Bg + (size_t)(bcol + r_) * 2048 + kt2_ + ce_);                       \
      gload16(gp_, SB + ((((T2) & 1) * 65536 + ((HF) >> 1) * 32768 +              \
                          ((HF) & 1) * 16384 + (s_ * 512 + w * 64) * 16) >> 1));  \
    }                                                                             \
  } while (0)

#define SQ_STAGE_ALL(T2)                                                          \
  do { SQ_STAGE_HALF(T2, 0); SQ_STAGE_HALF(T2, 1);                                \
       SQ_STAGE_HALF(T2, 2); SQ_STAGE_HALF(T2, 3); } while (0)

#define SQ_MFMA16x(AF, BF, MOFF)                                                  \
  do {                                                                            \
    _Pragma("unroll") for (int m_ = 0; m_ < 4; ++m_)                              \
      _Pragma("unroll") for (int n_ = 0; n_ < 4; ++n_)                            \
        acc[(MOFF) + m_][n_] = MFMA16(AF[m_], BF[n_], acc[(MOFF) + m_][n_]);      \
  } while (0)

#define SQ_TILE(CUR)                                                              \
  do {                                                                            \
    const char* Ab_ = (const char*)SB + (CUR) * 65536 + wr * 16384;               \
    const char* Bb_ = (const char*)SB + (CUR) * 65536 + 32768 +                   \
                      (wcn >> 1) * 16384 + (wcn & 1) * 8192;                      \
    bf16x8 a0_[4], a1_[4], a2_[4], a3_[4], b0_[4], b1_[4];                        \
    _Pragma("unroll") for (int n_ = 0; n_ < 4; ++n_)                              \
      b0_[n_] = ld_frag((const unsigned short*)(Bb_ + n_ * 2048 + la * 64 + cxa));\
    _Pragma("unroll") for (int m_ = 0; m_ < 4; ++m_)                              \
      a0_[m_] = ld_frag((const unsigned short*)(Ab_ + m_ * 2048 + la * 64 + cxa));\
    _Pragma("unroll") for (int m_ = 0; m_ < 4; ++m_)                              \
      a1_[m_] = ld_frag((const unsigned short*)(Ab_ + (4 + m_) * 2048 + la * 64 + cxa)); \
    asm volatile("s_waitcnt lgkmcnt(4)" ::: "memory");                            \
    __builtin_amdgcn_sched_barrier(0);                                            \
    SQ_MFMA16x(a0_, b0_, 0);                                                      \
    _Pragma("unroll") for (int n_ = 0; n_ < 4; ++n_)                              \
      b1_[n_] = ld_frag((const unsigned short*)(Bb_ + n_ * 2048 + 1024 + la * 64 + cxa)); \
    _Pragma("unroll") for (int m_ = 0; m_ < 4; ++m_)                              \
      a2_[m_] = ld_frag((const unsigned short*)(Ab_ + m_ * 2048 + 1024 + la * 64 + cxa)); \
    asm volatile("s_waitcnt lgkmcnt(8)" ::: "memory");                            \
    __builtin_amdgcn_sched_barrier(0);                                            \
    SQ_MFMA16x(a1_, b0_, 4);                                                      \
    _Pragma("unroll") for (int m_ = 0; m_ < 4; ++m_)                              \
      a3_[m_] = ld_frag((const unsigned short*)(Ab_ + (4 + m_) * 2048 + 1024 + la * 64 + cxa)); \
    asm volatile("s_waitcnt lgkmcnt(4)" ::: "memory");                            \
    __builtin_amdgcn_sched_barrier(0);                                            \
    SQ_MFMA16x(a2_, b1_, 0);                                                      \
    asm volatile("s_waitcnt lgkmcnt(0)" ::: "memory");                            \
    __builtin_amdgcn_sched_barrier(0);                                            \
    SQ_MFMA16x(a3_, b1_, 4);                                                      \
  } while (0)

__global__ __launch_bounds__(512, 1)
__attribute__((amdgpu_waves_per_eu(1, 2)))
void gemm_qkv256(const unsigned short* __restrict__ Ag,
                 const unsigned short* __restrict__ Bg,
                 unsigned short* __restrict__ Qp,
                 unsigned short* __restrict__ Kp,
                 unsigned short* __restrict__ Vtp) {
  __shared__ __align__(16) unsigned short SB[65536];   // 128 KiB
  const int tid = threadIdx.x, lane = tid & 63, w = tid >> 6;
  const int wr = w >> 2, wcn = w & 3;
  const int la = lane & 15, hi = lane >> 4;
  const int cxa = (hi * 16) ^ ((lane & 8) << 2);

  const int gx = gridDim.x;
  const int nwg = gx * gridDim.y;
  const int lid = blockIdx.y * gx + blockIdx.x;
  const int cpx = nwg >> 3;
  const int sz = (lid & 7) * cpx + (lid >> 3);
  const int bx = sz % gx, by = sz / gx;
  const int brow = by * 256, bcol = bx * 256;

  f32x4 acc[8][4] = {};

  SQ_STAGE_ALL(0);

#pragma unroll 1
  for (int t = 0; t < 32; ++t) {
    const int cur = t & 1;
    if (t < 31) {
      SQ_STAGE_ALL(t + 1);
      asm volatile("s_waitcnt vmcnt(8)" ::: "memory");
    } else {
      asm volatile("s_waitcnt vmcnt(0)" ::: "memory");
    }
    __builtin_amdgcn_sched_barrier(0);
    __builtin_amdgcn_s_barrier();

    SQ_TILE(cur);

    __builtin_amdgcn_s_barrier();
  }

  // epilogue: scatter Q (which=0), K (which=1), V^T (which=2)
#pragma unroll
  for (int mg = 0; mg < 8; ++mg) {
#pragma unroll
    for (int ng = 0; ng < 4; ++ng) {
      const int gcol = bcol + wcn * 64 + ng * 16 + la;
      const int grow0 = brow + wr * 128 + mg * 16 + hi * 4;
      const int which = gcol >> 11;
      const int c2 = gcol & 2047;
      const int hh = c2 >> 7, dd = c2 & 127;
      const int bb = grow0 >> 11, tt = grow0 & (SEQ - 1);
      if (which == 2) {
        u16x4 pk;
#pragma unroll
        for (int j = 0; j < 4; ++j) pk[j] = f2bf(acc[mg][ng][j]);
        *(u16x4*)&Vtp[(((size_t)bb * N_HEADS + hh) * HEAD_D + dd) * SEQ + tt] = pk;
      } else {
        unsigned short* dst = which ? Kp : Qp;
#pragma unroll
        for (int j = 0; j < 4; ++j)
          dst[(((size_t)bb * N_HEADS + hh) * SEQ + tt + j) * HEAD_D + dd] = f2bf(acc[mg][ng][j]);
      }
    }
  }
}

// ---------------- causal ALiBi flash attention (r18 best: step-major softmax + setprio) --
#define STAGE_KV(U, BSEL)                                                           \
  do {                                                                              \
    const int kv0_ = (((U) <= qtA) ? (U) : (U) - qtA - 1) * 64;                     \
    _Pragma("unroll")                                                               \
    for (int s = 0; s < 4; ++s) {                                                   \
      const int p_ = (w * 4 + s) * 1024 + lane * 16;                                \
      const int row_ = p_ >> 8, cb_ = p_ & 255;                                     \
      const int col_ = (cb_ ^ ((row_ & 7) << 4)) >> 1;                              \
      gload16(&K[kbase + (size_t)(kv0_ + row_) * HEAD_D + col_],                    \
              &Ks[BSEL][(w * 4 + s) * 512]);                                        \
    }                                                                               \
    _Pragma("unroll")                                                               \
    for (int s = 0; s < 4; ++s) {                                                   \
      const int p_ = (w * 4 + s) * 1024 + lane * 16;                                \
      const int d_ = p_ >> 7, cb_ = p_ & 127;                                       \
      const int col_ = (cb_ ^ ((d_ & 7) << 4)) >> 1;                                \
      gload16(&VT[vtbase + (size_t)d_ * SEQ + kv0_ + col_],                         \
              &Vs[BSEL][(w * 4 + s) * 512]);                                        \
    }                                                                               \
  } while (0)

#define LOAD_Q(Q0)                                                                  \
  do {                                                                              \
    const size_t qa_ = ((size_t)bh * SEQ + (Q0) + w * 16 + la) * HEAD_D + lq * 8;   \
    _Pragma("unroll")                                                               \
    for (int kk = 0; kk < 4; ++kk) qf[kk] = ld_frag(&Q[qa_ + kk * 32]);             \
  } while (0)

#define EPILOGUE(Q0)                                                                \
  do {                                                                              \
    _Pragma("unroll")                                                               \
    for (int j = 0; j < 4; ++j) {                                                   \
      const float inv_ = 1.0f / lrow[j];                                            \
      const int q_ = (Q0) + w * 16 + lq * 4 + j;                                    \
      const size_t ob_ = ((size_t)b * SEQ + q_) * D_MODEL + (size_t)h * HEAD_D;     \
      _Pragma("unroll")                                                             \
      for (int n = 0; n < 8; ++n) O[ob_ + n * 16 + la] = f2bf(acc[n][j] * inv_);    \
    }                                                                               \
  } while (0)

// step-major cross-lane reduces: the 4 rows' shfl chains interleave (~1/4 latency)
#define SOFTMAX_TILE(S, QG0, DIAG, KV0)                                            \
  do {                                                                             \
    float corr_[4];                                                                \
    float pe_[4][4];                                                               \
    float mx_[4];                                                                  \
    float rs_[4];                                                                  \
    _Pragma("unroll")                                                              \
    for (int j = 0; j < 4; ++j) {                                                  \
      const int qgj_ = (QG0) + j;                                                  \
      float m_ = -1e30f;                                                           \
      _Pragma("unroll")                                                            \
      for (int c = 0; c < 4; ++c) {                                                \
        const int kvg_ = (KV0) + c * 16 + la;                                      \
        float sv_ = fmaf(S[c][j], scale, slope * (float)(kvg_ - qgj_));            \
        if ((DIAG) && (kvg_ > qgj_)) sv_ = -1e30f;                                 \
        pe_[c][j] = sv_;                                                           \
        m_ = fmaxf(m_, sv_);                                                       \
      }                                                                            \
      mx_[j] = m_;                                                                 \
    }                                                                              \
    _Pragma("unroll")                                                              \
    for (int st = 1; st <= 8; st <<= 1) {                                          \
      _Pragma("unroll")                                                            \
      for (int j = 0; j < 4; ++j) mx_[j] = fmaxf(mx_[j], __shfl_xor(mx_[j], st));  \
    }                                                                              \
    _Pragma("unroll")                                                              \
    for (int j = 0; j < 4; ++j) {                                                  \
      const float nm_ = fmaxf(mrow[j], mx_[j]);                                    \
      corr_[j] = __expf(mrow[j] - nm_);                                            \
      mrow[j] = nm_;                                                               \
      float r_ = 0.f;                                                              \
      _Pragma("unroll")                                                            \
      for (int c = 0; c < 4; ++c) {                                                \
        const float e_ = __expf(pe_[c][j] - nm_);                                  \
        pe_[c][j] = e_;                                                            \
        r_ += e_;                                                                  \
      }                                                                            \
      rs_[j] = r_;                                                                 \
    }                                                                              \
    _Pragma("unroll")                                                              \
    for (int st = 1; st <= 8; st <<= 1) {                                          \
      _Pragma("unroll")                                                            \
      for (int j = 0; j < 4; ++j) rs_[j] += __shfl_xor(rs_[j], st);                \
    }                                                                              \
    _Pragma("unroll")                                                              \
    for (int j = 0; j < 4; ++j) lrow[j] = lrow[j] * corr_[j] + rs_[j];             \
    _Pragma("unroll")                                                              \
    for (int n = 0; n < 8; ++n) {                                                  \
      _Pragma("unroll")                                                            \
      for (int j = 0; j < 4; ++j) acc[n][j] *= corr_[j];                           \
    }                                                                              \
    _Pragma("unroll")                                                              \
    for (int c = 0; c < 4; ++c) {                                                  \
      _Pragma("unroll")                                                            \
      for (int j = 0; j < 4; ++j) {                                                \
        const int row_ = lq * 4 + j;                                               \
        const int cb_ = (c * 16 + la) * 2;                                         \
        *(unsigned short*)((char*)Ps[w] + row_ * 128 + (cb_ ^ ((row_ & 7) << 4)))  \
            = f2bf(pe_[c][j]);                                                     \
      }                                                                            \
    }                                                                              \
  } while (0)

__global__ __launch_bounds__(256)
void attn_k(const unsigned short* __restrict__ Q,
            const unsigned short* __restrict__ K,
            const unsigned short* __restrict__ VT,
            unsigned short* __restrict__ O) {
  __shared__ __align__(16) unsigned short Ks[2][64 * HEAD_D];   // 2x16 KB
  __shared__ __align__(16) unsigned short Vs[2][HEAD_D * 64];   // 2x16 KB
  __shared__ __align__(16) unsigned short Ps[4][16 * 64];       // 8 KB  (72 KB total)

  const int tid = threadIdx.x, lane = tid & 63, w = tid >> 6;
  const int lid = blockIdx.x;
  const int swz = (lid & 7) * 64 + (lid >> 3);
  const int qp = swz & 15;
  const int h  = (swz >> 4) & 15;
  const int b  = swz >> 8;
  const int bh = b * N_HEADS + h;
  const int qtA = qp, qtB = 31 - qp;
  const int q0A = qtA * 64, q0B = qtB * 64;

  const float slope = exp2f(-0.5f * (float)(h + 1));
  const float scale = 0.08838834764831845f;   // 1/sqrt(128)
  const int la = lane & 15;
  const int lq = lane >> 4;

  const size_t kbase  = (size_t)bh * SEQ * HEAD_D;
  const size_t vtbase = (size_t)bh * HEAD_D * SEQ;

  bf16x8 qf[4];
  f32x4 acc[8] = {};
  float mrow[4] = {-1e30f, -1e30f, -1e30f, -1e30f};
  float lrow[4] = {0.f, 0.f, 0.f, 0.f};
  int q0cur = q0A;

  LOAD_Q(q0A);
  STAGE_KV(0, 0);

  for (int u = 0; u < 33; ++u) {
    if (u < 32) {
      STAGE_KV(u + 1, (u + 1) & 1);
      asm volatile("s_waitcnt vmcnt(8)" ::: "memory");
    } else {
      asm volatile("s_waitcnt vmcnt(0)" ::: "memory");
    }
    __builtin_amdgcn_sched_barrier(0);
    __builtin_amdgcn_s_barrier();

    if (u == qtA + 1) {
      EPILOGUE(q0A);
      LOAD_Q(q0B);
      q0cur = q0B;
#pragma unroll
      for (int n = 0; n < 8; ++n)
#pragma unroll
        for (int j = 0; j < 4; ++j) acc[n][j] = 0.f;
#pragma unroll
      for (int j = 0; j < 4; ++j) { mrow[j] = -1e30f; lrow[j] = 0.f; }
    }

    const int cur = u & 1;
    const int kv0 = ((u <= qtA) ? u : u - qtA - 1) * 64;
    const bool diag = (u == qtA) || (u == 32);

    f32x4 s4[4] = {{0.f,0.f,0.f,0.f},{0.f,0.f,0.f,0.f},{0.f,0.f,0.f,0.f},{0.f,0.f,0.f,0.f}};
    __builtin_amdgcn_s_setprio(1);
#pragma unroll
    for (int c = 0; c < 4; ++c) {
      const int row = c * 16 + la;
#pragma unroll
      for (int kk = 0; kk < 4; ++kk) {
        const int cb = kk * 64 + lq * 16;
        bf16x8 kf = ld_frag((const unsigned short*)((const char*)Ks[cur] + row * 256 + (cb ^ ((row & 7) << 4))));
        s4[c] = MFMA16(qf[kk], kf, s4[c]);
      }
    }
    __builtin_amdgcn_s_setprio(0);

    SOFTMAX_TILE(s4, q0cur + w * 16 + lq * 4, diag, kv0);

    asm volatile("s_waitcnt lgkmcnt(0)" ::: "memory");
    __builtin_amdgcn_sched_barrier(0);

    __builtin_amdgcn_s_setprio(1);
#pragma unroll
    for (int kk = 0; kk < 2; ++kk) {
      const int pcb = kk * 64 + lq * 16;
      const int paddr = la * 128 + (pcb ^ ((la & 7) << 4));
      bf16x8 pf = ld_frag((const unsigned short*)((const char*)Ps[w] + paddr));
#pragma unroll
      for (int n = 0; n < 8; ++n) {
        const int d = n * 16 + la;
        bf16x8 vf = ld_frag((const unsigned short*)((const char*)Vs[cur] + d * 128 + (pcb ^ ((d & 7) << 4))));
        acc[n] = MFMA16(pf, vf, acc[n]);
      }
    }
    __builtin_amdgcn_s_setprio(0);

    __builtin_amdgcn_s_barrier();
  }

  EPILOGUE(q0B);
}

// ---------------- launcher ----------------
extern "C" void kernel_launch(void* const* d_in, const int* in_sizes, int n_in,
                              void* d_out, int out_size, void* d_ws, size_t ws_size,
                              hipStream_t stream) {
  (void)in_sizes; (void)n_in; (void)out_size; (void)ws_size;
  const float* x  = (const float*)d_in[0];
  const float* Wq = (const float*)d_in[1];
  const float* Wk = (const float*)d_in[2];
  const float* Wv = (const float*)d_in[3];
  const float* Wo = (const float*)d_in[4];

  char* ws = (char*)d_ws;
  unsigned short* xb = (unsigned short*)(ws + 0);          // 16 MiB
  unsigned short* wq = (unsigned short*)(ws + 16777216);   // 8 MiB  (wq|wk|wv|wo contiguous)
  unsigned short* wo = (unsigned short*)(ws + 41943040);   // 8 MiB
  unsigned short* q  = (unsigned short*)(ws + 50331648);   // 16 MiB
  unsigned short* k  = (unsigned short*)(ws + 67108864);   // 16 MiB
  unsigned short* vt = (unsigned short*)(ws + 83886080);   // 16 MiB
  unsigned short* o  = (unsigned short*)(ws + 0);          // aliases xb (dead after QKV GEMM)

  // one conversion dispatch: x (2^20 chunks) then wq|wk|wv|wo (2^21 chunks)
  f32_to_bf16_all<<<12288, 256, 0, stream>>>(x, Wq, Wk, Wv, Wo, xb);

  // fused QKV projection, v4b: grid (N/256, M/256) = (24, 16)
  gemm_qkv256<<<dim3(3 * D_MODEL / 256, MTOT / 256), 512, 0, stream>>>(xb, wq, q, k, vt);

  attn_k<<<512, 256, 0, stream>>>(q, k, vt, o);

  // O-projection (m97 structure, fp32 out)
  dim3 g2(D_MODEL / 128, MTOT / 128);       // (16, 32)
  gemm_bt_f32<<<g2, 256, 0, stream>>>(o, wo, (float*)d_out, MTOT, D_MODEL, D_MODEL);
}